// Round 3
// baseline (164.211 us; speedup 1.0000x reference)
//
#include <hip/hip_runtime.h>

// Problem constants (fixed by the reference's setup_inputs)
constexpr int B = 32;
constexpr int L = 256;
constexpr int H = 512;
constexpr int HV = H / 4;   // 128 float4 per row
constexpr int CHUNK = 32;   // output t-rows per block

typedef float f32x4 __attribute__((ext_vector_type(4)));

// Fused kernel: per-block cumsum recompute + chunked expansion.
// grid = (ceil(T/CHUNK), B), block = 256 threads.
// Each block writes out[b, t0:t0+CHUNK, :] (64 KB contiguous, non-temporal)
// + CHUNK mask floats.
__global__ __launch_bounds__(256) void lr_fused_kernel(
    const f32x4* __restrict__ x,    // (B, L, HV) float4
    const int* __restrict__ dur,    // (B, L)
    f32x4* __restrict__ out,        // (B, T, HV) float4
    float* __restrict__ mask,       // (B, T)
    int T) {
    __shared__ int sc[L];
    const int b = blockIdx.y;
    const int tid = threadIdx.x;    // 0..255

    // --- inclusive scan of durations for batch b (Hillis-Steele, 8 steps) ---
    sc[tid] = dur[b * L + tid];
    __syncthreads();
    #pragma unroll
    for (int off = 1; off < L; off <<= 1) {
        int t = (tid >= off) ? sc[tid - off] : 0;
        __syncthreads();
        sc[tid] += t;
        __syncthreads();
    }
    const int total = sc[L - 1];

    // --- expansion: two t-rows per iteration (halves of the block) ---
    const int t0 = blockIdx.x * CHUNK;
    const int half = tid >> 7;      // 0 or 1
    const int lane = tid & 127;     // float4 lane within the row

    // searchsorted(csum, t, 'right') for this half's first t: first idx with
    // sc[idx] > t. Uniform within each half -> LDS broadcast, no divergence.
    const int tfirst = t0 + half;
    int lo = 0, hi = L;
    while (lo < hi) {
        int mid = (lo + hi) >> 1;
        if (sc[mid] <= tfirst) lo = mid + 1; else hi = mid;
    }
    int idx = lo;   // in [0, L]

    #pragma unroll
    for (int i = 0; i < CHUNK / 2; ++i) {
        const int t = t0 + 2 * i + half;
        // monotone advance (t increases by 2 per iter; few total advances/chunk)
        while (idx < L && sc[idx] <= t) ++idx;
        const int gidx = (idx < L - 1) ? idx : (L - 1);  // clip to L-1
        if (t < T) {
            f32x4 val = (f32x4){0.f, 0.f, 0.f, 0.f};
            if (t < total) {
                val = x[((size_t)(b * L + gidx)) * HV + lane];
            }
            // Streaming store: out is write-once, never re-read — keep it from
            // evicting x's L2 lines (x rows are re-read ~7.5x on average).
            __builtin_nontemporal_store(val, &out[((size_t)b * T + t) * HV + lane]);
        }
    }

    // --- mask: CHUNK consecutive floats per block, coalesced ---
    if (tid < CHUNK) {
        const int t = t0 + tid;
        if (t < T) {
            mask[(size_t)b * T + t] = (t < total) ? 1.0f : 0.0f;
        }
    }
}

extern "C" void kernel_launch(void* const* d_in, const int* in_sizes, int n_in,
                              void* d_out, int out_size, void* d_ws, size_t ws_size,
                              hipStream_t stream) {
    const float* x = (const float*)d_in[0];       // (B, L, H) fp32
    const int* dur = (const int*)d_in[1];         // (B, L) int32
    float* out = (float*)d_out;

    // out_size = B*T*H + B*T = B*T*(H+1)  ->  T
    const int T = out_size / (B * (H + 1));

    float* mask_out = out + (size_t)B * T * H;
    dim3 grid((T + CHUNK - 1) / CHUNK, B);
    lr_fused_kernel<<<grid, 256, 0, stream>>>((const f32x4*)x, dur,
                                              (f32x4*)out, mask_out, T);
}

// Round 4
// 154.754 us; speedup vs baseline: 1.0611x; 1.0611x over previous
//
#include <hip/hip_runtime.h>

// Problem constants (fixed by the reference's setup_inputs)
constexpr int B = 32;
constexpr int L = 256;
constexpr int H = 512;
constexpr int HV = H / 4;   // 128 float4 per row
constexpr int CHUNK = 16;   // output t-rows per block (16 > 32: measured R2 vs R3)

// Fused kernel: per-block cumsum recompute + chunked expansion.
// grid = (ceil(T/CHUNK), B), block = 256 threads.
// Each block writes out[b, t0:t0+CHUNK, :] (32 KB contiguous) + 16 mask floats.
// Plain stores (NT stores measured neutral-to-negative in R3: x is L3-resident,
// so L2 write pollution costs nothing in HBM bytes).
__global__ __launch_bounds__(256) void lr_fused_kernel(
    const float4* __restrict__ x,   // (B, L, HV) float4
    const int* __restrict__ dur,    // (B, L)
    float4* __restrict__ out,       // (B, T, HV) float4
    float* __restrict__ mask,       // (B, T)
    int T) {
    __shared__ int sc[L];
    const int b = blockIdx.y;
    const int tid = threadIdx.x;    // 0..255

    // --- inclusive scan of durations for batch b (Hillis-Steele, 8 steps) ---
    sc[tid] = dur[b * L + tid];
    __syncthreads();
    #pragma unroll
    for (int off = 1; off < L; off <<= 1) {
        int t = (tid >= off) ? sc[tid - off] : 0;
        __syncthreads();
        sc[tid] += t;
        __syncthreads();
    }
    const int total = sc[L - 1];

    // --- expansion: two t-rows per iteration (halves of the block) ---
    const int t0 = blockIdx.x * CHUNK;
    const int half = tid >> 7;      // 0 or 1
    const int lane = tid & 127;     // float4 lane within the row

    // searchsorted(csum, t, 'right') for this half's first t: first idx with
    // sc[idx] > t. Uniform within each half -> LDS broadcast, no divergence.
    const int tfirst = t0 + half;
    int lo = 0, hi = L;
    while (lo < hi) {
        int mid = (lo + hi) >> 1;
        if (sc[mid] <= tfirst) lo = mid + 1; else hi = mid;
    }
    int idx = lo;   // in [0, L]

    #pragma unroll
    for (int i = 0; i < CHUNK / 2; ++i) {
        const int t = t0 + 2 * i + half;
        // monotone advance (t increases by 2 per iter; ~2 total advances/chunk)
        while (idx < L && sc[idx] <= t) ++idx;
        const int gidx = (idx < L - 1) ? idx : (L - 1);  // clip to L-1
        if (t < T) {
            float4 val = make_float4(0.f, 0.f, 0.f, 0.f);
            if (t < total) {
                val = x[((size_t)(b * L + gidx)) * HV + lane];
            }
            out[((size_t)b * T + t) * HV + lane] = val;
        }
    }

    // --- mask: 16 consecutive floats per block, coalesced ---
    if (tid < CHUNK) {
        const int t = t0 + tid;
        if (t < T) {
            mask[(size_t)b * T + t] = (t < total) ? 1.0f : 0.0f;
        }
    }
}

extern "C" void kernel_launch(void* const* d_in, const int* in_sizes, int n_in,
                              void* d_out, int out_size, void* d_ws, size_t ws_size,
                              hipStream_t stream) {
    const float* x = (const float*)d_in[0];       // (B, L, H) fp32
    const int* dur = (const int*)d_in[1];         // (B, L) int32
    float* out = (float*)d_out;

    // out_size = B*T*H + B*T = B*T*(H+1)  ->  T
    const int T = out_size / (B * (H + 1));

    float* mask_out = out + (size_t)B * T * H;
    dim3 grid((T + CHUNK - 1) / CHUNK, B);
    lr_fused_kernel<<<grid, 256, 0, stream>>>((const float4*)x, dur,
                                              (float4*)out, mask_out, T);
}